// Round 4
// baseline (620.660 us; speedup 1.0000x reference)
//
#include <hip/hip_runtime.h>

#define NB    2
#define NDST  131072
#define NSRC  131072
#define FF    64
#define EE    524288
#define EPSV  1e-8f
#define SCAN_BLOCKS 512      // NDST / 256
#define NWG_H 128            // histogram/fill workgroups
#define BPW   1024           // bins per WG  (NWG_H * BPW == NDST)

typedef unsigned long long u64;

// ---------- Phase A: atomic-free histogram ----------
// Each WG owns bins [w*BPW, (w+1)*BPW), streams the whole dst array (L2-resident),
// counts its bins in LDS, writes counts with plain stores (exclusive ownership).
__global__ __launch_bounds__(256) void hist2_kernel(const int4* __restrict__ dst4,
                                                    int* __restrict__ counts) {
    __shared__ int cnt[BPW];
    int t = threadIdx.x;
    int lo = blockIdx.x * BPW;
    for (int i = t; i < BPW; i += 256) cnt[i] = 0;
    __syncthreads();
    for (int i = t; i < EE / 4; i += 256) {
        int4 v = dst4[i];
        int a;
        a = v.x - lo; if ((unsigned)a < BPW) atomicAdd(&cnt[a], 1);
        a = v.y - lo; if ((unsigned)a < BPW) atomicAdd(&cnt[a], 1);
        a = v.z - lo; if ((unsigned)a < BPW) atomicAdd(&cnt[a], 1);
        a = v.w - lo; if ((unsigned)a < BPW) atomicAdd(&cnt[a], 1);
    }
    __syncthreads();
    for (int i = t; i < BPW; i += 256) counts[lo + i] = cnt[i];
}

// ---------- Phase B: exclusive scan of counts (3 kernels) ----------
__global__ void scan1_kernel(const int* __restrict__ counts,
                             int* __restrict__ offs, int* __restrict__ bsum) {
    __shared__ int tmp[256];
    int t = threadIdx.x;
    int i = blockIdx.x * 256 + t;
    int v = counts[i];
    tmp[t] = v; __syncthreads();
    for (int off = 1; off < 256; off <<= 1) {
        int add = (t >= off) ? tmp[t - off] : 0;
        __syncthreads();
        tmp[t] += add;
        __syncthreads();
    }
    offs[i] = tmp[t] - v;                     // exclusive within block
    if (t == 255) bsum[blockIdx.x] = tmp[t];  // block total
}

__global__ void scan2_kernel(int* __restrict__ bsum) {
    __shared__ int tmp[SCAN_BLOCKS];
    int t = threadIdx.x;
    int v = bsum[t];
    tmp[t] = v; __syncthreads();
    for (int off = 1; off < SCAN_BLOCKS; off <<= 1) {
        int add = (t >= off) ? tmp[t - off] : 0;
        __syncthreads();
        tmp[t] += add;
        __syncthreads();
    }
    bsum[t] = tmp[t] - v;                     // exclusive
}

__global__ void scan3_kernel(int* __restrict__ offs, const int* __restrict__ bsum) {
    int i = blockIdx.x * 256 + threadIdx.x;
    offs[i] += bsum[blockIdx.x];
    if (i == 0) offs[NDST] = EE;
}

// ---------- Phase C: atomic-free (global) counting sort ----------
// Same partitioning as hist2: LDS cursors seeded from offs; stream dst; for edges
// in range, place packed (w<<32|src) record. Positions claimed via LDS atomics only.
__global__ __launch_bounds__(256) void fill2_kernel(const int* __restrict__ src,
                                                    const int4* __restrict__ dst4,
                                                    const float* __restrict__ wts,
                                                    const int* __restrict__ offs,
                                                    u64* __restrict__ rec) {
    __shared__ int cur[BPW];
    int t = threadIdx.x;
    int lo = blockIdx.x * BPW;
    for (int i = t; i < BPW; i += 256) cur[i] = offs[lo + i];
    __syncthreads();
    for (int i = t; i < EE / 4; i += 256) {
        int4 v = dst4[i];
        int e = i * 4;
        int a;
        a = v.x - lo; if ((unsigned)a < BPW) {
            int p = atomicAdd(&cur[a], 1);
            rec[p] = ((u64)__float_as_uint(wts[e + 0]) << 32) | (unsigned)src[e + 0];
        }
        a = v.y - lo; if ((unsigned)a < BPW) {
            int p = atomicAdd(&cur[a], 1);
            rec[p] = ((u64)__float_as_uint(wts[e + 1]) << 32) | (unsigned)src[e + 1];
        }
        a = v.z - lo; if ((unsigned)a < BPW) {
            int p = atomicAdd(&cur[a], 1);
            rec[p] = ((u64)__float_as_uint(wts[e + 2]) << 32) | (unsigned)src[e + 2];
        }
        a = v.w - lo; if ((unsigned)a < BPW) {
            int p = atomicAdd(&cur[a], 1);
            rec[p] = ((u64)__float_as_uint(wts[e + 3]) << 32) | (unsigned)src[e + 3];
        }
    }
}

// ---------- Phase D: one wave per dst; unroll-4 segment loop; nt out stores ----------
// out[b,d,f] = (sum_e w_e * x[b, s_e, f]) / (sum_e w_e + eps)
__global__ __launch_bounds__(256) void gather_kernel(const float* __restrict__ x,
                                                     const int* __restrict__ offs,
                                                     const u64* __restrict__ rec,
                                                     float* __restrict__ out) {
    int gid  = blockIdx.x * blockDim.x + threadIdx.x;
    int d    = gid >> 6;       // one wave per destination node
    int lane = gid & 63;       // lane = feature index (F == 64)

    int begin = offs[d];
    int end   = offs[d + 1];

    const float* xb0 = x + lane;                          // b = 0
    const float* xb1 = x + (size_t)NSRC * FF + lane;      // b = 1

    float acc0 = 0.f, acc1 = 0.f, sumw = 0.f;
    int e = begin;
    for (; e + 4 <= end; e += 4) {
        u64 r0 = rec[e + 0];
        u64 r1 = rec[e + 1];
        u64 r2 = rec[e + 2];
        u64 r3 = rec[e + 3];
        int s0 = (int)(unsigned)r0;  float w0 = __uint_as_float((unsigned)(r0 >> 32));
        int s1 = (int)(unsigned)r1;  float w1 = __uint_as_float((unsigned)(r1 >> 32));
        int s2 = (int)(unsigned)r2;  float w2 = __uint_as_float((unsigned)(r2 >> 32));
        int s3 = (int)(unsigned)r3;  float w3 = __uint_as_float((unsigned)(r3 >> 32));
        float a00 = xb0[(size_t)s0 * FF];
        float a10 = xb0[(size_t)s1 * FF];
        float a20 = xb0[(size_t)s2 * FF];
        float a30 = xb0[(size_t)s3 * FF];
        float a01 = xb1[(size_t)s0 * FF];
        float a11 = xb1[(size_t)s1 * FF];
        float a21 = xb1[(size_t)s2 * FF];
        float a31 = xb1[(size_t)s3 * FF];
        sumw += (w0 + w1) + (w2 + w3);
        acc0 = fmaf(w0, a00, fmaf(w1, a10, fmaf(w2, a20, fmaf(w3, a30, acc0))));
        acc1 = fmaf(w0, a01, fmaf(w1, a11, fmaf(w2, a21, fmaf(w3, a31, acc1))));
    }
    for (; e < end; ++e) {
        u64 r = rec[e];
        int s = (int)(unsigned)r;
        float w = __uint_as_float((unsigned)(r >> 32));
        sumw += w;
        acc0 = fmaf(w, xb0[(size_t)s * FF], acc0);
        acc1 = fmaf(w, xb1[(size_t)s * FF], acc1);
    }
    float inv = 1.0f / (sumw + EPSV);
    __builtin_nontemporal_store(acc0 * inv, &out[(size_t)d * FF + lane]);
    __builtin_nontemporal_store(acc1 * inv, &out[(size_t)NDST * FF + (size_t)d * FF + lane]);
}

extern "C" void kernel_launch(void* const* d_in, const int* in_sizes, int n_in,
                              void* d_out, int out_size, void* d_ws, size_t ws_size,
                              hipStream_t stream) {
    const float* x          = (const float*)d_in[0];
    const int*   edge_index = (const int*)d_in[1];   // (2, E) int32
    const float* weights    = (const float*)d_in[2];

    const int*  src  = edge_index;
    const int4* dst4 = (const int4*)(edge_index + EE);
    float* out = (float*)d_out;

    // Workspace layout (4 B units):
    int* wsi    = (int*)d_ws;
    int* counts = wsi;                               // NDST
    int* offs   = wsi + NDST;                        // NDST + 1
    int* bsum   = wsi + 2 * NDST + 8;                // SCAN_BLOCKS
    u64* rec    = (u64*)(wsi + 2 * NDST + 8 + SCAN_BLOCKS);  // EE u64 (8B-aligned)

    hist2_kernel<<<NWG_H, 256, 0, stream>>>(dst4, counts);
    scan1_kernel<<<SCAN_BLOCKS, 256, 0, stream>>>(counts, offs, bsum);
    scan2_kernel<<<1, SCAN_BLOCKS, 0, stream>>>(bsum);
    scan3_kernel<<<SCAN_BLOCKS, 256, 0, stream>>>(offs, bsum);
    fill2_kernel<<<NWG_H, 256, 0, stream>>>(src, dst4, weights, offs, rec);
    gather_kernel<<<(NDST * 64) / 256, 256, 0, stream>>>(x, offs, rec, out);
}

// Round 5
// 189.287 us; speedup vs baseline: 3.2789x; 3.2789x over previous
//
#include <hip/hip_runtime.h>

#define NB    2
#define NDST  131072
#define NSRC  131072
#define FF    64
#define EE    524288
#define EPSV  1e-8f
#define SCAN_BLOCKS 512      // scans 131072 = 512*256 elements
#define NBUCK 256            // buckets (dst >> 9), 512 dst bins per bucket
#define NB1   512            // pass-1 blocks; each handles EE/NB1 = 1024 edges
#define CAP   4096           // max edges per bucket staged in LDS (mean 2048, sd ~45)

typedef unsigned long long u64;

// ---------- k1: per-block bucket histogram (LDS atomics only) ----------
__global__ __launch_bounds__(256) void histA_kernel(const int* __restrict__ dst,
                                                    int* __restrict__ histg) {
    __shared__ int cnt[NBUCK];
    int t = threadIdx.x;
    int b = blockIdx.x;
    for (int i = t; i < NBUCK; i += 256) cnt[i] = 0;
    __syncthreads();
    int base = b * 1024;
    #pragma unroll
    for (int it = 0; it < 4; ++it) {
        int d = dst[base + it * 256 + t];
        atomicAdd(&cnt[d >> 9], 1);
    }
    __syncthreads();
    for (int i = t; i < NBUCK; i += 256) histg[i * NB1 + b] = cnt[i];
}

// ---------- k2: exclusive scan of 131072 counters (3 kernels) ----------
__global__ void scan1_kernel(const int* __restrict__ counts,
                             int* __restrict__ offs, int* __restrict__ bsum) {
    __shared__ int tmp[256];
    int t = threadIdx.x;
    int i = blockIdx.x * 256 + t;
    int v = counts[i];
    tmp[t] = v; __syncthreads();
    for (int off = 1; off < 256; off <<= 1) {
        int add = (t >= off) ? tmp[t - off] : 0;
        __syncthreads();
        tmp[t] += add;
        __syncthreads();
    }
    offs[i] = tmp[t] - v;
    if (t == 255) bsum[blockIdx.x] = tmp[t];
}

__global__ void scan2_kernel(int* __restrict__ bsum) {
    __shared__ int tmp[SCAN_BLOCKS];
    int t = threadIdx.x;
    int v = bsum[t];
    tmp[t] = v; __syncthreads();
    for (int off = 1; off < SCAN_BLOCKS; off <<= 1) {
        int add = (t >= off) ? tmp[t - off] : 0;
        __syncthreads();
        tmp[t] += add;
        __syncthreads();
    }
    bsum[t] = tmp[t] - v;
}

__global__ void scan3_kernel(int* __restrict__ posg, const int* __restrict__ bsum) {
    int i = blockIdx.x * 256 + threadIdx.x;
    posg[i] += bsum[blockIdx.x];
    if (i == 0) posg[NBUCK * NB1] = EE;   // end sentinel
}

// ---------- k3: place edges into bucket order (LDS cursors, no global atomics) ----
// tmp_rec = w(32) | local_bin(9 @bit17) | src(17)
__global__ __launch_bounds__(256) void scatterA_kernel(const int* __restrict__ src,
                                                       const int* __restrict__ dst,
                                                       const float* __restrict__ wts,
                                                       const int* __restrict__ posg,
                                                       u64* __restrict__ tmp_rec) {
    __shared__ int cur[NBUCK];
    int t = threadIdx.x;
    int b = blockIdx.x;
    cur[t] = posg[t * NB1 + b];     // NBUCK == 256 == blockDim
    __syncthreads();
    int base = b * 1024;
    #pragma unroll
    for (int it = 0; it < 4; ++it) {
        int e = base + it * 256 + t;
        int d = dst[e];
        int p = atomicAdd(&cur[d >> 9], 1);
        u64 r = ((u64)__float_as_uint(wts[e]) << 32)
              | ((u64)(d & 511) << 17)
              | (unsigned)src[e];
        tmp_rec[p] = r;
    }
}

// ---------- k4: within-bucket counting sort to exact dst; writes offs + rec ------
__global__ __launch_bounds__(256) void bucket_kernel(const int* __restrict__ posg,
                                                     const u64* __restrict__ tmp_rec,
                                                     int* __restrict__ offs,
                                                     u64* __restrict__ rec) {
    __shared__ u64 ld_rec[CAP];
    __shared__ unsigned short ld_bin[CAP];
    __shared__ int cnt[512];
    __shared__ int excl[512];
    __shared__ int s[256];

    int t = threadIdx.x;
    int k = blockIdx.x;
    int lo = posg[k * NB1];
    int hi = posg[(k + 1) * NB1];
    int n  = hi - lo;
    if (n > CAP) n = CAP;   // statistically impossible for uniform random dst

    for (int j = t; j < 512; j += 256) cnt[j] = 0;
    __syncthreads();

    for (int i = t; i < n; i += 256) {
        u64 r = tmp_rec[lo + i];
        int bin = (int)((r >> 17) & 511);
        ld_rec[i] = r;
        ld_bin[i] = (unsigned short)bin;
        atomicAdd(&cnt[bin], 1);
    }
    __syncthreads();

    // block scan of cnt[512] -> excl[512] (2 bins per thread)
    int a0 = cnt[2 * t], a1 = cnt[2 * t + 1];
    s[t] = a0 + a1;
    __syncthreads();
    for (int off = 1; off < 256; off <<= 1) {
        int add = (t >= off) ? s[t - off] : 0;
        __syncthreads();
        s[t] += add;
        __syncthreads();
    }
    int ex = s[t] - (a0 + a1);
    excl[2 * t]     = ex;
    excl[2 * t + 1] = ex + a0;
    __syncthreads();

    // per-dst offsets (global)
    offs[k * 512 + t]       = lo + excl[t];
    offs[k * 512 + t + 256] = lo + excl[t + 256];
    if (k == NBUCK - 1 && t == 0) offs[NDST] = EE;

    // reuse cnt as cursor
    cnt[2 * t]     = lo + excl[2 * t];
    cnt[2 * t + 1] = lo + excl[2 * t + 1];
    __syncthreads();

    const u64 mask = (((u64)0xFFFFFFFFu) << 32) | 0x1FFFFu;  // keep w + src
    for (int i = t; i < n; i += 256) {
        int bin = ld_bin[i];
        int p = atomicAdd(&cnt[bin], 1);
        rec[p] = ld_rec[i] & mask;
    }
}

// ---------- k5: gather — one wave per dst; unroll-4; nt out stores ----------
__global__ __launch_bounds__(256) void gather_kernel(const float* __restrict__ x,
                                                     const int* __restrict__ offs,
                                                     const u64* __restrict__ rec,
                                                     float* __restrict__ out) {
    int gid  = blockIdx.x * blockDim.x + threadIdx.x;
    int d    = gid >> 6;
    int lane = gid & 63;

    int begin = offs[d];
    int end   = offs[d + 1];

    const float* xb0 = x + lane;
    const float* xb1 = x + (size_t)NSRC * FF + lane;

    float acc0 = 0.f, acc1 = 0.f, sumw = 0.f;
    int e = begin;
    for (; e + 4 <= end; e += 4) {
        u64 r0 = rec[e + 0];
        u64 r1 = rec[e + 1];
        u64 r2 = rec[e + 2];
        u64 r3 = rec[e + 3];
        int s0 = (int)(unsigned)r0;  float w0 = __uint_as_float((unsigned)(r0 >> 32));
        int s1 = (int)(unsigned)r1;  float w1 = __uint_as_float((unsigned)(r1 >> 32));
        int s2 = (int)(unsigned)r2;  float w2 = __uint_as_float((unsigned)(r2 >> 32));
        int s3 = (int)(unsigned)r3;  float w3 = __uint_as_float((unsigned)(r3 >> 32));
        float a00 = xb0[(size_t)s0 * FF];
        float a10 = xb0[(size_t)s1 * FF];
        float a20 = xb0[(size_t)s2 * FF];
        float a30 = xb0[(size_t)s3 * FF];
        float a01 = xb1[(size_t)s0 * FF];
        float a11 = xb1[(size_t)s1 * FF];
        float a21 = xb1[(size_t)s2 * FF];
        float a31 = xb1[(size_t)s3 * FF];
        sumw += (w0 + w1) + (w2 + w3);
        acc0 = fmaf(w0, a00, fmaf(w1, a10, fmaf(w2, a20, fmaf(w3, a30, acc0))));
        acc1 = fmaf(w0, a01, fmaf(w1, a11, fmaf(w2, a21, fmaf(w3, a31, acc1))));
    }
    for (; e < end; ++e) {
        u64 r = rec[e];
        int s = (int)(unsigned)r;
        float w = __uint_as_float((unsigned)(r >> 32));
        sumw += w;
        acc0 = fmaf(w, xb0[(size_t)s * FF], acc0);
        acc1 = fmaf(w, xb1[(size_t)s * FF], acc1);
    }
    float inv = 1.0f / (sumw + EPSV);
    __builtin_nontemporal_store(acc0 * inv, &out[(size_t)d * FF + lane]);
    __builtin_nontemporal_store(acc1 * inv, &out[(size_t)NDST * FF + (size_t)d * FF + lane]);
}

extern "C" void kernel_launch(void* const* d_in, const int* in_sizes, int n_in,
                              void* d_out, int out_size, void* d_ws, size_t ws_size,
                              hipStream_t stream) {
    const float* x          = (const float*)d_in[0];
    const int*   edge_index = (const int*)d_in[1];   // (2, E) int32
    const float* weights    = (const float*)d_in[2];

    const int* src = edge_index;
    const int* dst = edge_index + EE;
    float* out = (float*)d_out;

    // Workspace layout (u64 arrays first for 8B alignment):
    char* w8 = (char*)d_ws;
    u64* tmp_rec = (u64*)w8;                          // EE u64   = 4 MB
    u64* rec     = (u64*)(w8 + (size_t)EE * 8);       // EE u64   = 4 MB
    int* histg   = (int*)(w8 + (size_t)EE * 16);      // 131072   = 512 KB
    int* posg    = histg + NBUCK * NB1;               // 131072+8 (incl. sentinel)
    int* bsum    = posg + NBUCK * NB1 + 8;            // SCAN_BLOCKS
    int* offs    = bsum + SCAN_BLOCKS;                // NDST + 8

    histA_kernel<<<NB1, 256, 0, stream>>>(dst, histg);
    scan1_kernel<<<SCAN_BLOCKS, 256, 0, stream>>>(histg, posg, bsum);
    scan2_kernel<<<1, SCAN_BLOCKS, 0, stream>>>(bsum);
    scan3_kernel<<<SCAN_BLOCKS, 256, 0, stream>>>(posg, bsum);
    scatterA_kernel<<<NB1, 256, 0, stream>>>(src, dst, weights, posg, tmp_rec);
    bucket_kernel<<<NBUCK, 256, 0, stream>>>(posg, tmp_rec, offs, rec);
    gather_kernel<<<(NDST * 64) / 256, 256, 0, stream>>>(x, offs, rec, out);
}

// Round 6
// 181.041 us; speedup vs baseline: 3.4283x; 1.0456x over previous
//
#include <hip/hip_runtime.h>

#define NB    2
#define NDST  131072
#define NSRC  131072
#define FF    64
#define EE    524288
#define EPSV  1e-8f

#define NBUCK 2048           // buckets = dst >> 6  (64 dst per bucket)
#define NB1   512            // pass-1 blocks; each handles EE/NB1 = 1024 edges
#define NCNT  (NBUCK * NB1)  // 1,048,576 counters
#define SCAN_BLOCKS (NCNT / 256)   // 4096
#define CAPB  512            // max edges per bucket in LDS (mean 256, sd 16)

typedef unsigned long long u64;

// ---------- k1: per-block bucket histogram (LDS atomics only) ----------
__global__ __launch_bounds__(256) void histA_kernel(const int* __restrict__ dst,
                                                    int* __restrict__ histg) {
    __shared__ int cnt[NBUCK];
    int t = threadIdx.x;
    int b = blockIdx.x;
    for (int i = t; i < NBUCK; i += 256) cnt[i] = 0;
    __syncthreads();
    int base = b * 1024;
    #pragma unroll
    for (int it = 0; it < 4; ++it) {
        int d = dst[base + it * 256 + t];
        atomicAdd(&cnt[d >> 6], 1);
    }
    __syncthreads();
    for (int i = t; i < NBUCK; i += 256) histg[i * NB1 + b] = cnt[i];
}

// ---------- k2: exclusive scan of 1,048,576 counters (3 kernels) ----------
__global__ void scan1_kernel(const int* __restrict__ counts,
                             int* __restrict__ offs, int* __restrict__ bsum) {
    __shared__ int tmp[256];
    int t = threadIdx.x;
    int i = blockIdx.x * 256 + t;
    int v = counts[i];
    tmp[t] = v; __syncthreads();
    for (int off = 1; off < 256; off <<= 1) {
        int add = (t >= off) ? tmp[t - off] : 0;
        __syncthreads();
        tmp[t] += add;
        __syncthreads();
    }
    offs[i] = tmp[t] - v;
    if (t == 255) bsum[blockIdx.x] = tmp[t];
}

__global__ __launch_bounds__(1024) void scan2_kernel(int* __restrict__ bsum) {
    __shared__ int tmp[1024];
    int t = threadIdx.x;
    int v0 = bsum[4 * t], v1 = bsum[4 * t + 1], v2 = bsum[4 * t + 2], v3 = bsum[4 * t + 3];
    int s = v0 + v1 + v2 + v3;
    tmp[t] = s; __syncthreads();
    for (int off = 1; off < 1024; off <<= 1) {
        int add = (t >= off) ? tmp[t - off] : 0;
        __syncthreads();
        tmp[t] += add;
        __syncthreads();
    }
    int ex = tmp[t] - s;
    bsum[4 * t]     = ex;
    bsum[4 * t + 1] = ex + v0;
    bsum[4 * t + 2] = ex + v0 + v1;
    bsum[4 * t + 3] = ex + v0 + v1 + v2;
}

__global__ void scan3_kernel(int* __restrict__ posg, const int* __restrict__ bsum) {
    int i = blockIdx.x * 256 + threadIdx.x;
    posg[i] += bsum[blockIdx.x];
    if (i == 0) posg[NCNT] = EE;   // end sentinel
}

// ---------- k3: place edges into bucket order (LDS cursors, no global atomics) ----
// tmp_rec = w(32) | local_bin6(@bit17) | src(17)
__global__ __launch_bounds__(256) void scatterA_kernel(const int* __restrict__ src,
                                                       const int* __restrict__ dst,
                                                       const float* __restrict__ wts,
                                                       const int* __restrict__ posg,
                                                       u64* __restrict__ tmp_rec) {
    __shared__ int cur[NBUCK];
    int t = threadIdx.x;
    int b = blockIdx.x;
    for (int i = t; i < NBUCK; i += 256) cur[i] = posg[i * NB1 + b];
    __syncthreads();
    int base = b * 1024;
    #pragma unroll
    for (int it = 0; it < 4; ++it) {
        int e = base + it * 256 + t;
        int d = dst[e];
        int p = atomicAdd(&cur[d >> 6], 1);
        u64 r = ((u64)__float_as_uint(wts[e]) << 32)
              | ((u64)(d & 63) << 17)
              | (unsigned)src[e];
        tmp_rec[p] = r;
    }
}

// ---------- k4: fused within-bucket sort + gather ----------
// One block per bucket (64 dst, ~256 edges). Stage records in LDS, 64-bin
// count + wave scan + LDS reorder, then 4 waves x 16 dst gather from LDS recs.
__global__ __launch_bounds__(256) void fused_kernel(const float* __restrict__ x,
                                                    const int* __restrict__ posg,
                                                    const u64* __restrict__ tmp_rec,
                                                    float* __restrict__ out) {
    __shared__ u64 stage[CAPB];
    __shared__ u64 sorted[CAPB];
    __shared__ int cnt[64];
    __shared__ int loffs[65];

    int t = threadIdx.x;
    int k = blockIdx.x;
    int lo = posg[k * NB1];
    int hi = posg[(k + 1) * NB1];     // sentinel covers k == NBUCK-1
    int n  = hi - lo;
    if (n > CAPB) n = CAPB;           // statistically impossible

    if (t < 64) cnt[t] = 0;
    __syncthreads();

    for (int i = t; i < n; i += 256) {
        u64 r = tmp_rec[lo + i];
        stage[i] = r;
        atomicAdd(&cnt[(int)((r >> 17) & 63)], 1);
    }
    __syncthreads();

    // wave 0: inclusive shuffle-scan of the 64 bins
    if (t < 64) {
        int c = cnt[t];
        int incl = c;
        #pragma unroll
        for (int off = 1; off < 64; off <<= 1) {
            int o = __shfl_up(incl, off, 64);
            if (t >= off) incl += o;
        }
        loffs[t + 1] = incl;
        if (t == 0) loffs[0] = 0;
        cnt[t] = incl - c;            // exclusive -> cursor
    }
    __syncthreads();

    for (int i = t; i < n; i += 256) {
        u64 r = stage[i];
        int p = atomicAdd(&cnt[(int)((r >> 17) & 63)], 1);
        sorted[p] = r;
    }
    __syncthreads();

    // gather: wave w handles local dst [w*16, w*16+16)
    int wave = t >> 6, lane = t & 63;
    const float* xb0 = x + lane;
    const float* xb1 = x + (size_t)NSRC * FF + lane;

    for (int dl = wave * 16; dl < wave * 16 + 16; ++dl) {
        int begin = loffs[dl];
        int end   = loffs[dl + 1];
        float acc0 = 0.f, acc1 = 0.f, sumw = 0.f;
        int e = begin;
        for (; e + 4 <= end; e += 4) {
            u64 r0 = sorted[e + 0];
            u64 r1 = sorted[e + 1];
            u64 r2 = sorted[e + 2];
            u64 r3 = sorted[e + 3];
            int s0 = (int)(r0 & 0x1FFFF);  float w0 = __uint_as_float((unsigned)(r0 >> 32));
            int s1 = (int)(r1 & 0x1FFFF);  float w1 = __uint_as_float((unsigned)(r1 >> 32));
            int s2 = (int)(r2 & 0x1FFFF);  float w2 = __uint_as_float((unsigned)(r2 >> 32));
            int s3 = (int)(r3 & 0x1FFFF);  float w3 = __uint_as_float((unsigned)(r3 >> 32));
            float a00 = xb0[(size_t)s0 * FF];
            float a10 = xb0[(size_t)s1 * FF];
            float a20 = xb0[(size_t)s2 * FF];
            float a30 = xb0[(size_t)s3 * FF];
            float a01 = xb1[(size_t)s0 * FF];
            float a11 = xb1[(size_t)s1 * FF];
            float a21 = xb1[(size_t)s2 * FF];
            float a31 = xb1[(size_t)s3 * FF];
            sumw += (w0 + w1) + (w2 + w3);
            acc0 = fmaf(w0, a00, fmaf(w1, a10, fmaf(w2, a20, fmaf(w3, a30, acc0))));
            acc1 = fmaf(w0, a01, fmaf(w1, a11, fmaf(w2, a21, fmaf(w3, a31, acc1))));
        }
        for (; e < end; ++e) {
            u64 r = sorted[e];
            int s = (int)(r & 0x1FFFF);
            float w = __uint_as_float((unsigned)(r >> 32));
            sumw += w;
            acc0 = fmaf(w, xb0[(size_t)s * FF], acc0);
            acc1 = fmaf(w, xb1[(size_t)s * FF], acc1);
        }
        float inv = 1.0f / (sumw + EPSV);
        int d = k * 64 + dl;
        __builtin_nontemporal_store(acc0 * inv, &out[(size_t)d * FF + lane]);
        __builtin_nontemporal_store(acc1 * inv, &out[(size_t)NDST * FF + (size_t)d * FF + lane]);
    }
}

extern "C" void kernel_launch(void* const* d_in, const int* in_sizes, int n_in,
                              void* d_out, int out_size, void* d_ws, size_t ws_size,
                              hipStream_t stream) {
    const float* x          = (const float*)d_in[0];
    const int*   edge_index = (const int*)d_in[1];   // (2, E) int32
    const float* weights    = (const float*)d_in[2];

    const int* src = edge_index;
    const int* dst = edge_index + EE;
    float* out = (float*)d_out;

    // Workspace: histg (4MB) is dead after scan1, so tmp_rec aliases it.
    int* histg   = (int*)d_ws;                 // NCNT ints   = 4 MB
    u64* tmp_rec = (u64*)d_ws;                 // EE u64      = 4 MB (alias, lifetime disjoint)
    int* posg    = histg + NCNT;               // NCNT + 8 ints (incl. sentinel)
    int* bsum    = posg + NCNT + 8;            // SCAN_BLOCKS = 4096 ints

    histA_kernel<<<NB1, 256, 0, stream>>>(dst, histg);
    scan1_kernel<<<SCAN_BLOCKS, 256, 0, stream>>>(histg, posg, bsum);
    scan2_kernel<<<1, 1024, 0, stream>>>(bsum);
    scan3_kernel<<<SCAN_BLOCKS, 256, 0, stream>>>(posg, bsum);
    scatterA_kernel<<<NB1, 256, 0, stream>>>(src, dst, weights, posg, tmp_rec);
    fused_kernel<<<NBUCK, 256, 0, stream>>>(x, posg, tmp_rec, out);
}